// Round 5
// baseline (1082.897 us; speedup 1.0000x reference)
//
#include <hip/hip_runtime.h>

#define HIDDEN 51
#define LSEQ 1000
#define NK 26   // k-columns per wave: wave0 k=0..25, wave1 k=26..51 (51 = zero pad)

// Branch-free tanh: tanh(v) = 1 - 2/(exp2(2*log2e*v)+1). Saturates to +/-1.
__device__ __forceinline__ float fast_tanh(float v) {
    float e = __builtin_amdgcn_exp2f(v * 2.885390081777927f);  // 2*log2(e)
    float r = __builtin_amdgcn_rcpf(e + 1.0f);
    return fmaf(-2.0f, r, 1.0f);
}

// Two waves per batch element, k-split (26 U-columns x 4 gates = 104 regs per
// wave). Both waves hold bitwise-identical h/c (gate = own + other partial,
// float add commutes), so h is broadcast with v_readlane from each wave's OWN
// h register -- no LDS round-trip, no barrier for h (R4's h-store->h-load
// serial dependency removed). The only per-step LDS is the partial-gate
// exchange: one ds_write_b128 + barrier + one ds_read_b128, parity
// double-buffered -> exactly one __syncthreads per step. Output dot runs one
// step behind on wave1 only (wave0 does the x-projection instead), so the
// swizzle chain hides under the FMA block.
__global__ __launch_bounds__(128, 2) void lstm_seq_kernel(
    const float* __restrict__ x,
    const float* __restrict__ W_w,
    const float* __restrict__ W_b,
    const float* __restrict__ U_w,
    const float* __restrict__ U_b,
    const float* __restrict__ lin_w,
    const float* __restrict__ lin_b,
    float* __restrict__ out)
{
    __shared__ float pg[2][2][64][4];    // [t&1][wid][lane][gate] exchange

    const int b    = blockIdx.x;
    const int tid  = threadIdx.x;
    const int wid  = tid >> 6;           // 0 or 1
    const int lane = tid & 63;
    const bool active = lane < HIDDEN;   // lanes 51..63 produce exact zeros
    const int m = active ? lane : 0;

    // x-projection + fused bias, carried by wave0 only (counted once).
    float ww[4], bb[4];
#pragma unroll
    for (int g = 0; g < 4; ++g) {
        const int row = m + g * HIDDEN;
        ww[g] = (active && wid == 0) ? W_w[row] : 0.f;
        bb[g] = (active && wid == 0) ? (W_b[row] + U_b[row]) : 0.f;
    }
    // Output dot weights live on wave1 (the butterfly wave).
    const float lw = (active && wid == 1) ? lin_w[m] : 0.f;
    const float lb = lin_b[0];

    // U columns for this wave: k = wid*NK + j. k==51 zero-padded. (Inactive
    // lanes zero their rows so their h stays exactly 0 -> readlane(h,51)==0.)
    float U[NK][4];
#pragma unroll
    for (int j = 0; j < NK; ++j) {
        const int k = wid * NK + j;
#pragma unroll
        for (int g = 0; g < 4; ++g) {
            const int row = m + g * HIDDEN;
            U[j][g] = (active && k < HIDDEN) ? U_w[row * HIDDEN + k] : 0.f;
        }
    }

    const int kbase = wid * NK;          // wave-uniform -> SGPR readlane index

    float h = 0.f, c = 0.f, red = 0.f;
    const float* __restrict__ xrow = x + (long)b * LSEQ;
    float* __restrict__ orow = out + (long)b * LSEQ;

    float x_cur = xrow[0];  // wave-uniform scalar load
    for (int t = 0; t < LSEQ; ++t) {
        const int tn = (t + 1 < LSEQ) ? (t + 1) : t;
        float x_next = xrow[tn];
        const int par = t & 1;

        // Wave0: fold in the x-term. Wave1: pipelined butterfly for the
        // PREVIOUS step's output (red = h_{t-1} * lw). Wave-uniform branch.
        float p0, p1, p2, p3;
        float r = red;
        if (wid == 0) {
            p0 = fmaf(x_cur, ww[0], bb[0]);
            p1 = fmaf(x_cur, ww[1], bb[1]);
            p2 = fmaf(x_cur, ww[2], bb[2]);
            p3 = fmaf(x_cur, ww[3], bb[3]);
        } else {
            p0 = p1 = p2 = p3 = 0.f;
#pragma unroll
            for (int off = 32; off > 0; off >>= 1)
                r += __shfl_xor(r, off, 64);
        }

        // h broadcast via readlane from this wave's own (identical) h.
        // Index kbase+j is wave-uniform (SGPR) -- legal, zero latency.
#pragma unroll
        for (int j = 0; j < NK; ++j) {
            const float hk = __builtin_bit_cast(
                float, __builtin_amdgcn_readlane(__builtin_bit_cast(int, h),
                                                 kbase + j));
            p0 = fmaf(hk, U[j][0], p0);
            p1 = fmaf(hk, U[j][1], p1);
            p2 = fmaf(hk, U[j][2], p2);
            p3 = fmaf(hk, U[j][3], p3);
        }

        // Store previous step's output (wave1 lane0), off the critical path.
        const int ot = (t > 0) ? (t - 1) : 0;
        if (tid == 64) orow[ot] = r + lb;

        // Exchange partials: one b128 each way, ONE barrier, parity-buffered.
        *(float4*)&pg[par][wid][lane][0] = make_float4(p0, p1, p2, p3);
        __syncthreads();
        const float4 po = *(const float4*)&pg[par][1 - wid][lane][0];

        // own + other commutes exactly -> bitwise-identical on both waves.
        const float gi = p0 + po.x;
        const float gf = p1 + po.y;
        const float gg = p2 + po.z;
        const float go = p3 + po.w;

        // NOTE: faithful to reference -- no sigmoid on gates.
        c = fmaf(gf, c, gi * gg);
        const float th = fast_tanh(c);
        h = go * th;
        red = h * lw;

        x_cur = x_next;
    }

    // Drain: output for t = LSEQ-1 (butterfly result only valid on wave1).
#pragma unroll
    for (int off = 32; off > 0; off >>= 1)
        red += __shfl_xor(red, off, 64);
    if (tid == 64) orow[LSEQ - 1] = red + lb;
}

extern "C" void kernel_launch(void* const* d_in, const int* in_sizes, int n_in,
                              void* d_out, int out_size, void* d_ws, size_t ws_size,
                              hipStream_t stream) {
    const float* x     = (const float*)d_in[0];
    const float* W_w   = (const float*)d_in[1];
    const float* W_b   = (const float*)d_in[2];
    const float* U_w   = (const float*)d_in[3];
    const float* U_b   = (const float*)d_in[4];
    const float* lin_w = (const float*)d_in[5];
    const float* lin_b = (const float*)d_in[6];
    // d_in[7] = future (static 0; out_size == B*LSEQ)
    float* out = (float*)d_out;

    const int B = in_sizes[0] / LSEQ;  // 1024
    lstm_seq_kernel<<<dim3(B), dim3(128), 0, stream>>>(
        x, W_w, W_b, U_w, U_b, lin_w, lin_b, out);
}

// Round 6
// 718.271 us; speedup vs baseline: 1.5076x; 1.5076x over previous
//
#include <hip/hip_runtime.h>

#define HIDDEN 51
#define LSEQ 1000
#define NK 26   // k-columns per wave: wave0 k=0..25, wave1 k=26..51 (51 = zero pad)

// Branch-free tanh: tanh(v) = 1 - 2/(exp2(2*log2e*v)+1). Saturates to +/-1.
__device__ __forceinline__ float fast_tanh(float v) {
    float e = __builtin_amdgcn_exp2f(v * 2.885390081777927f);  // 2*log2(e)
    float r = __builtin_amdgcn_rcpf(e + 1.0f);
    return fmaf(-2.0f, r, 1.0f);
}

// Two waves per batch element, k-split (26 U-columns x 4 gates = 104 regs/wave).
// Both waves hold bitwise-identical h/c (gate = own + other partial; float add
// commutes), so each wave broadcasts h from its OWN register via v_readlane
// with COMPILE-TIME-CONSTANT lane indices (R5 lesson: an index derived from
// tid is not provably uniform -> per-readlane waterfall, +700 cyc/step).
// The role split is a scalar-uniform branch on readfirstlane(wid), with the
// FMA block cloned per wave so all readlane indices are literals.
// Per-step LDS: one ds_write_b128 + one barrier + one ds_read_b128 (parity
// double-buffered pg exchange). Output dot runs one step behind on wave1.
__global__ __launch_bounds__(128, 2) void lstm_seq_kernel(
    const float* __restrict__ x,
    const float* __restrict__ W_w,
    const float* __restrict__ W_b,
    const float* __restrict__ U_w,
    const float* __restrict__ U_b,
    const float* __restrict__ lin_w,
    const float* __restrict__ lin_b,
    float* __restrict__ out)
{
    __shared__ float pg[2][2][64][4];    // [t&1][wid][lane][gate] exchange

    const int b    = blockIdx.x;
    const int tid  = threadIdx.x;
    const int wid  = tid >> 6;           // 0 or 1
    const int lane = tid & 63;
    const bool active = lane < HIDDEN;   // lanes 51..63 produce exact zeros
    const int m = active ? lane : 0;

    // Scalar-uniform wave id (SGPR) -> s_cmp/s_cbranch, no exec masking.
    const int swid = __builtin_amdgcn_readfirstlane(wid);

    // x-projection + fused bias, carried by wave0 only (counted once).
    float ww[4], bb[4];
#pragma unroll
    for (int g = 0; g < 4; ++g) {
        const int row = m + g * HIDDEN;
        ww[g] = (active && swid == 0) ? W_w[row] : 0.f;
        bb[g] = (active && swid == 0) ? (W_b[row] + U_b[row]) : 0.f;
    }
    // Output dot weights live on wave1 (the butterfly wave).
    const float lw = (active && swid == 1) ? lin_w[m] : 0.f;
    const float lb = lin_b[0];

    // U columns for this wave: k = swid*NK + j. k==51 zero-padded. Inactive
    // lanes zero their rows so their h stays exactly 0 -> readlane(h,51)==0.
    float U[NK][4];
#pragma unroll
    for (int j = 0; j < NK; ++j) {
        const int k = swid * NK + j;
#pragma unroll
        for (int g = 0; g < 4; ++g) {
            const int row = m + g * HIDDEN;
            U[j][g] = (active && k < HIDDEN) ? U_w[row * HIDDEN + k] : 0.f;
        }
    }

    float h = 0.f, c = 0.f, red = 0.f;
    const float* __restrict__ xrow = x + (long)b * LSEQ;
    float* __restrict__ orow = out + (long)b * LSEQ;

    float x_cur = (swid == 0) ? xrow[0] : 0.f;  // only wave0 touches x
    for (int t = 0; t < LSEQ; ++t) {
        const int par = t & 1;
        float x_next = x_cur;
        float p0, p1, p2, p3;
        float r = red;

        if (swid == 0) {
            // ---- wave0: x-term + k = 0..25 (constant readlane indices) ----
            const int tn = (t + 1 < LSEQ) ? (t + 1) : t;
            x_next = xrow[tn];
            p0 = fmaf(x_cur, ww[0], bb[0]);
            p1 = fmaf(x_cur, ww[1], bb[1]);
            p2 = fmaf(x_cur, ww[2], bb[2]);
            p3 = fmaf(x_cur, ww[3], bb[3]);
#pragma unroll
            for (int j = 0; j < NK; ++j) {
                const float hk = __builtin_bit_cast(
                    float,
                    __builtin_amdgcn_readlane(__builtin_bit_cast(int, h), j));
                p0 = fmaf(hk, U[j][0], p0);
                p1 = fmaf(hk, U[j][1], p1);
                p2 = fmaf(hk, U[j][2], p2);
                p3 = fmaf(hk, U[j][3], p3);
            }
        } else {
            // ---- wave1: pipelined output butterfly + k = 26..51 ----
            p0 = p1 = p2 = p3 = 0.f;
#pragma unroll
            for (int off = 32; off > 0; off >>= 1)
                r += __shfl_xor(r, off, 64);
#pragma unroll
            for (int j = 0; j < NK; ++j) {
                const float hk = __builtin_bit_cast(
                    float,
                    __builtin_amdgcn_readlane(__builtin_bit_cast(int, h),
                                              NK + j));  // literal 26..51
                p0 = fmaf(hk, U[j][0], p0);
                p1 = fmaf(hk, U[j][1], p1);
                p2 = fmaf(hk, U[j][2], p2);
                p3 = fmaf(hk, U[j][3], p3);
            }
            // Store previous step's output (lane 0), before the barrier so
            // the store issues early; nothing waits on it.
            const int ot = (t > 0) ? (t - 1) : 0;
            if (lane == 0) orow[ot] = r + lb;
        }

        // Exchange partials: one b128 each way, ONE barrier, parity-buffered.
        *(float4*)&pg[par][wid][lane][0] = make_float4(p0, p1, p2, p3);
        __syncthreads();
        const float4 po = *(const float4*)&pg[par][1 - wid][lane][0];

        // own + other commutes exactly -> bitwise-identical on both waves.
        const float gi = p0 + po.x;
        const float gf = p1 + po.y;
        const float gg = p2 + po.z;
        const float go = p3 + po.w;

        // NOTE: faithful to reference -- no sigmoid on gates.
        c = fmaf(gf, c, gi * gg);
        const float th = fast_tanh(c);
        h = go * th;
        red = h * lw;

        x_cur = x_next;
    }

    // Drain: output for t = LSEQ-1 (meaningful only on wave1; wave0's lw=0).
#pragma unroll
    for (int off = 32; off > 0; off >>= 1)
        red += __shfl_xor(red, off, 64);
    if (tid == 64) orow[LSEQ - 1] = red + lb;
}

extern "C" void kernel_launch(void* const* d_in, const int* in_sizes, int n_in,
                              void* d_out, int out_size, void* d_ws, size_t ws_size,
                              hipStream_t stream) {
    const float* x     = (const float*)d_in[0];
    const float* W_w   = (const float*)d_in[1];
    const float* W_b   = (const float*)d_in[2];
    const float* U_w   = (const float*)d_in[3];
    const float* U_b   = (const float*)d_in[4];
    const float* lin_w = (const float*)d_in[5];
    const float* lin_b = (const float*)d_in[6];
    // d_in[7] = future (static 0; out_size == B*LSEQ)
    float* out = (float*)d_out;

    const int B = in_sizes[0] / LSEQ;  // 1024
    lstm_seq_kernel<<<dim3(B), dim3(128), 0, stream>>>(
        x, W_w, W_b, U_w, U_b, lin_w, lin_b, out);
}